// Round 4
// baseline (972.029 us; speedup 1.0000x reference)
//
#include <hip/hip_runtime.h>
#include <hip/hip_bf16.h>

// AFNO2D: B=4, H=128, W=128, C=768, 8 blocks x 96ch, FACTOR=1, lambda=0.01
// Pipeline: rfftW -> fftH -> blockMLP(bf16 MFMA) -> ifftH -> irfftW(+bias)
// Freq buffer F: [b][h][wf=65][c=768] float2, in d_ws (204.5 MB), in-place for
// stages 2-4.

#define PI_F 3.14159265358979323846f

typedef __attribute__((ext_vector_type(8))) short short8;
typedef __attribute__((ext_vector_type(4))) float f32x4;

__device__ __host__ constexpr int BR6(int v) {
  return ((v & 1) << 5) | ((v & 2) << 3) | ((v & 4) << 1) |
         ((v & 8) >> 1) | ((v & 16) >> 3) | ((v & 32) >> 5);
}

__device__ __forceinline__ unsigned short f2bf(float f) {
  unsigned int u = __float_as_uint(f);
  u += 0x7FFFu + ((u >> 16) & 1u);   // RNE
  return (unsigned short)(u >> 16);
}

// In-register 64-point complex FFT, DIT, input must be in bit-reversed order,
// output natural order. DIR=-1: e^{-i}, DIR=+1: e^{+i}. Twiddle table:
// ct[k]=cos(2pi k/128), st[k]=sin(2pi k/128) (LDS, broadcast reads).
template <int DIR>
__device__ __forceinline__ void fft64_reg(float (&zr)[64], float (&zi)[64],
                                          const float* ct, const float* st) {
#pragma unroll
  for (int s = 0; s < 6; ++s) {
    const int half = 1 << s;
#pragma unroll
    for (int j = 0; j < 32; ++j) {
      const int pos = j & (half - 1);
      const int i1 = ((j >> s) << (s + 1)) + pos;
      const int i2 = i1 + half;
      const int idx = (pos << (5 - s)) << 1;  // *2: index into /128 table
      const float wr = ct[idx];
      const float wi = (float)DIR * st[idx];
      const float tr = wr * zr[i2] - wi * zi[i2];
      const float ti = wr * zi[i2] + wi * zr[i2];
      zr[i2] = zr[i1] - tr; zi[i2] = zi[i1] - ti;
      zr[i1] += tr;         zi[i1] += ti;
    }
  }
}

// ---------------- Stage 1: rfft along W (ortho scale 1/128 applied) --------
__global__ void __launch_bounds__(256) k_fwdw(const float* __restrict__ x,
                                              float2* __restrict__ F) {
  __shared__ float ct[64], st[64];
  const int t = threadIdx.x;
  if (t < 64) { float sv, cv; sincosf(PI_F * (float)t / 64.0f, &sv, &cv); ct[t] = cv; st[t] = sv; }
  __syncthreads();
  const int gid = blockIdx.x * 256 + t;
  const int c = gid % 768;
  const int rem = gid / 768;
  const int h = rem & 127, b = rem >> 7;
  const float* px = x + ((size_t)(b * 128 + h) * 128) * 768 + c;

  float zr[64], zi[64];
#pragma unroll
  for (int m = 0; m < 64; ++m) {
    const int mb = BR6(m);  // bit-reversed load order for DIT
    zr[m] = px[(size_t)(2 * mb) * 768];
    zi[m] = px[(size_t)(2 * mb + 1) * 768];
  }
  fft64_reg<-1>(zr, zi, ct, st);

  float2* pf = F + ((size_t)(b * 128 + h) * 65) * 768 + c;
  const float sc = 1.0f / 128.0f;  // full 2D ortho forward scale
#pragma unroll
  for (int k = 0; k <= 32; ++k) {
    const int mk = (64 - k) & 63;
    const float ar  = 0.5f * (zr[k] + zr[mk]);
    const float ai  = 0.5f * (zi[k] - zi[mk]);
    const float br_ = 0.5f * (zr[k] - zr[mk]);
    const float bi  = 0.5f * (zi[k] + zi[mk]);
    // T = e^{-2pi i k/128} * B
    const float tr = ct[k] * br_ + st[k] * bi;
    const float ti = ct[k] * bi - st[k] * br_;
    pf[(size_t)k * 768]        = make_float2(sc * (ar + ti), sc * (ai - tr));
    pf[(size_t)(64 - k) * 768] = make_float2(sc * (ar - ti), sc * (-ai - tr));
  }
}

// ---------------- Stages 2 & 4: 128-pt complex FFT along H (in place) ------
// DIR=-1 forward, DIR=+1 inverse (raw sum; scaling handled elsewhere).
template <int DIR>
__global__ void __launch_bounds__(256) k_ffth(float2* __restrict__ F) {
  __shared__ float sr[128 * 33];
  __shared__ float si[128 * 33];
  __shared__ float ct[64], st[64];
  const int t = threadIdx.x;
  if (t < 64) { float sv, cv; sincosf(PI_F * (float)t / 64.0f, &sv, &cv); ct[t] = cv; st[t] = sv; }
  const int bx = blockIdx.x;
  const int ctile = bx % 24;
  const int rem = bx / 24;
  const int wf = rem % 65, b = rem / 65;
  const size_t base = ((size_t)b * 128 * 65 + wf) * 768 + ctile * 32;

#pragma unroll
  for (int rep = 0; rep < 8; ++rep) {
    const int ll = rep * 256 + t;
    const int c2 = (ll & 15) * 2;
    const int h = ll >> 4;
    const float4 v = *(const float4*)(F + base + (size_t)h * 49920 + c2);
    const int hb = (int)(__brev((unsigned)h) >> 25);  // bit-rev 7
    sr[hb * 33 + c2]     = v.x; si[hb * 33 + c2]     = v.y;
    sr[hb * 33 + c2 + 1] = v.z; si[hb * 33 + c2 + 1] = v.w;
  }
  __syncthreads();

  for (int s = 0; s < 7; ++s) {
    const int half = 1 << s;
#pragma unroll
    for (int rep = 0; rep < 8; ++rep) {
      const int u = rep * 256 + t;
      const int c = u & 31;
      const int j = u >> 5;
      const int pos = j & (half - 1);
      const int i1 = ((j >> s) << (s + 1)) + pos;
      const int i2 = i1 + half;
      const int idx = pos << (6 - s);
      const float wr = ct[idx];
      const float wi = (float)DIR * st[idx];
      const int a1 = i1 * 33 + c, a2 = i2 * 33 + c;
      const float xr = sr[a2], xi = si[a2];
      const float tr = wr * xr - wi * xi;
      const float ti = wr * xi + wi * xr;
      const float yr = sr[a1], yi = si[a1];
      sr[a2] = yr - tr; si[a2] = yi - ti;
      sr[a1] = yr + tr; si[a1] = yi + ti;
    }
    __syncthreads();
  }

#pragma unroll
  for (int rep = 0; rep < 8; ++rep) {
    const int ll = rep * 256 + t;
    const int c2 = (ll & 15) * 2;
    const int h = ll >> 4;
    const float4 v = make_float4(sr[h * 33 + c2], si[h * 33 + c2],
                                 sr[h * 33 + c2 + 1], si[h * 33 + c2 + 1]);
    *(float4*)(F + base + (size_t)h * 49920 + c2) = v;
  }
}

// ---------------- Weight prep: pack to bf16 in MFMA fragment order ---------
// Wg[n][ks(6)][nf(12)][lane(64)][j(8)] <-> B[k=ks*32+(lane>>4)*8+j][o2=nf*16+(lane&15)]
// Packed complex GEMM: B[k][o2<96] = k<96 ? Wr[k][o2] : -Wi[k-96][o2]
//                      B[k][o2>=96] = k<96 ? Wi[k][o2-96] : Wr[k-96][o2-96]
__device__ unsigned short packw(const float* __restrict__ w, int f) {
  const int j = f & 7;
  const int lane = (f >> 3) & 63;
  const int t2 = f >> 9;
  const int nf = t2 % 12;
  const int t3 = t2 / 12;
  const int ks = t3 % 6;
  const int n = t3 / 6;
  const int k = ks * 32 + (lane >> 4) * 8 + j;
  const int o2 = nf * 16 + (lane & 15);
  float val;
  if (o2 < 96) {
    if (k < 96) val =  w[n * 9216 + k * 96 + o2];
    else        val = -w[73728 + n * 9216 + (k - 96) * 96 + o2];
  } else {
    const int o = o2 - 96;
    if (k < 96) val =  w[73728 + n * 9216 + k * 96 + o];
    else        val =  w[n * 9216 + (k - 96) * 96 + o];
  }
  return f2bf(val);
}

__global__ void __launch_bounds__(256) k_prep(
    const float* __restrict__ w1, const float* __restrict__ b1,
    const float* __restrict__ w2, const float* __restrict__ b2,
    unsigned short* __restrict__ W1, unsigned short* __restrict__ W2,
    float* __restrict__ B1, float* __restrict__ B2) {
  const int gid = blockIdx.x * 256 + threadIdx.x;
  if (gid < 294912) {
    W1[gid] = packw(w1, gid);
  } else if (gid < 589824) {
    W2[gid - 294912] = packw(w2, gid - 294912);
  } else if (gid < 591360) {
    const int i = gid - 589824;
    const int n = i / 192, o2 = i % 192;
    B1[i] = (o2 < 96) ? b1[n * 96 + o2] : b1[768 + n * 96 + (o2 - 96)];
  } else if (gid < 592896) {
    const int i = gid - 591360;
    const int n = i / 192, o2 = i % 192;
    B2[i] = (o2 < 96) ? b2[n * 96 + o2] : b2[768 + n * 96 + (o2 - 96)];
  }
}

// ---------------- Stage 3: block-diagonal complex MLP (bf16 MFMA) ----------
// Grid (520, 8): 64-position tile x block n. 256 thr = 4 waves, wave w owns
// rows [16w,16w+16). A/O1 staged in LDS in exact MFMA fragment order.
__global__ void __launch_bounds__(256) k_mlp(float* __restrict__ Ff,
                                             const unsigned short* __restrict__ W1g,
                                             const unsigned short* __restrict__ W2g,
                                             const float* __restrict__ B1,
                                             const float* __restrict__ B2) {
  __shared__ __align__(16) short A1[12288];  // [mb4][ks6][lane64][j8]
  __shared__ __align__(16) short A2[12288];
  const int t = threadIdx.x;
  const int p0 = blockIdx.x * 64;
  const int n = blockIdx.y;

  // ---- stage A-tile: F complex -> bf16 [Xr | Xi] in fragment order
  {
    const int r = t >> 2, q = t & 3;
    const float4* src =
        (const float4*)(Ff + ((size_t)(p0 + r) * 768 + n * 96 + q * 24) * 2);
    unsigned int re32[12], im32[12];
#pragma unroll
    for (int u = 0; u < 12; ++u) {
      const float4 v = src[u];  // channels q*24+2u (x,y), q*24+2u+1 (z,w)
      re32[u] = (unsigned)f2bf(v.x) | ((unsigned)f2bf(v.z) << 16);
      im32[u] = (unsigned)f2bf(v.y) | ((unsigned)f2bf(v.w) << 16);
    }
    const int mb = r >> 4, r16 = r & 15;
#pragma unroll
    for (int g = 0; g < 3; ++g) {
      const int k0 = q * 24 + g * 8;  // real k; imag k = k0 + 96
      {
        const int ks = k0 >> 5, kg = (k0 >> 3) & 3;
        const int idx = ((mb * 6 + ks) * 64 + kg * 16 + r16) * 8;
        *(int4*)&A1[idx] = make_int4(re32[4 * g], re32[4 * g + 1],
                                     re32[4 * g + 2], re32[4 * g + 3]);
      }
      {
        const int k1 = k0 + 96;
        const int ks = k1 >> 5, kg = (k1 >> 3) & 3;
        const int idx = ((mb * 6 + ks) * 64 + kg * 16 + r16) * 8;
        *(int4*)&A1[idx] = make_int4(im32[4 * g], im32[4 * g + 1],
                                     im32[4 * g + 2], im32[4 * g + 3]);
      }
    }
  }
  __syncthreads();

  const int w = t >> 6, l = t & 63;
  const int colBase = l & 15;
  const int rgrp = (l >> 4) << 2;

  // ---- layer 1: O1 = relu(A @ W1pack + b1pack)
  f32x4 acc[12];
#pragma unroll
  for (int nf = 0; nf < 12; ++nf) {
    const float bv = B1[n * 192 + nf * 16 + colBase];
    acc[nf] = f32x4{bv, bv, bv, bv};
  }
  const short8* Ap = (const short8*)A1;
  const short8* w1p = (const short8*)(W1g + (size_t)n * 36864);
#pragma unroll
  for (int ks = 0; ks < 6; ++ks) {
    const short8 a = Ap[(w * 6 + ks) * 64 + l];
#pragma unroll
    for (int nf = 0; nf < 12; ++nf) {
      const short8 bb = w1p[(ks * 12 + nf) * 64 + l];
      acc[nf] = __builtin_amdgcn_mfma_f32_16x16x32_bf16(a, bb, acc[nf], 0, 0, 0);
    }
  }
  // relu -> A2 fragment order (C/D layout: row=(l>>4)*4+rr, col=l&15)
#pragma unroll
  for (int nf = 0; nf < 12; ++nf) {
    const int o2b = nf * 16 + colBase;
    const int ks2 = o2b >> 5, kg2 = (o2b >> 3) & 3, j2 = o2b & 7;
#pragma unroll
    for (int rr = 0; rr < 4; ++rr) {
      const float vv = fmaxf(acc[nf][rr], 0.0f);
      const int lane2 = kg2 * 16 + rgrp + rr;
      A2[((w * 6 + ks2) * 64 + lane2) * 8 + j2] = (short)f2bf(vv);
    }
  }
  __syncthreads();

  // ---- layer 2: O2 = O1 @ W2pack + b2pack
#pragma unroll
  for (int nf = 0; nf < 12; ++nf) {
    const float bv = B2[n * 192 + nf * 16 + colBase];
    acc[nf] = f32x4{bv, bv, bv, bv};
  }
  const short8* A2p = (const short8*)A2;
  const short8* w2p = (const short8*)(W2g + (size_t)n * 36864);
#pragma unroll
  for (int ks = 0; ks < 6; ++ks) {
    const short8 a = A2p[(w * 6 + ks) * 64 + l];
#pragma unroll
    for (int nf = 0; nf < 12; ++nf) {
      const short8 bb = w2p[(ks * 12 + nf) * 64 + l];
      acc[nf] = __builtin_amdgcn_mfma_f32_16x16x32_bf16(a, bb, acc[nf], 0, 0, 0);
    }
  }
  // ---- softshrink + scatter back into F (real/imag halves of float2)
#pragma unroll
  for (int nf = 0; nf < 12; ++nf) {
    const int o2 = nf * 16 + colBase;
    const int isIm = (o2 >= 96) ? 1 : 0;
    const int cch = n * 96 + (isIm ? o2 - 96 : o2);
#pragma unroll
    for (int rr = 0; rr < 4; ++rr) {
      const int p = p0 + w * 16 + rgrp + rr;
      const float vv = acc[nf][rr];
      const float av = fabsf(vv) - 0.01f;
      const float res = (av > 0.0f) ? copysignf(av, vv) : 0.0f;
      Ff[((size_t)p * 768 + cch) * 2 + isIm] = res;
    }
  }
}

// ---------------- Stage 5: irfft along W + residual ------------------------
__global__ void __launch_bounds__(256) k_invw(const float2* __restrict__ F,
                                              const float* __restrict__ x,
                                              float* __restrict__ out) {
  __shared__ float ct[64], st[64];
  const int t = threadIdx.x;
  if (t < 64) { float sv, cv; sincosf(PI_F * (float)t / 64.0f, &sv, &cv); ct[t] = cv; st[t] = sv; }
  __syncthreads();
  const int gid = blockIdx.x * 256 + t;
  const int c = gid % 768;
  const int rem = gid / 768;
  const int h = rem & 127, b = rem >> 7;
  const float2* pf = F + ((size_t)(b * 128 + h) * 65) * 768 + c;

  float zr[64], zi[64];
  {
    // bins 0 and 64: c2r semantics use real part only
    const float2 u0 = pf[0];
    const float2 uN = pf[(size_t)64 * 768];
    zr[0] = 0.5f * (u0.x + uN.x);
    zi[0] = 0.5f * (u0.x - uN.x);
    const float2 uM = pf[(size_t)32 * 768];
    zr[BR6(32)] = uM.x;
    zi[BR6(32)] = -uM.y;
  }
#pragma unroll
  for (int k = 1; k < 32; ++k) {
    const float2 uk = pf[(size_t)k * 768];
    const float2 um = pf[(size_t)(64 - k) * 768];
    const float er  = 0.5f * (uk.x + um.x);
    const float ei  = 0.5f * (uk.y - um.y);
    const float br_ = 0.5f * (uk.x - um.x);
    const float bi  = 0.5f * (uk.y + um.y);
    // O = e^{+2pi i k/128} * B
    const float or_ = ct[k] * br_ - st[k] * bi;
    const float oi  = ct[k] * bi + st[k] * br_;
    zr[BR6(k)] = er - oi;       zi[BR6(k)] = ei + or_;
    zr[BR6(64 - k)] = er + oi;  zi[BR6(64 - k)] = or_ - ei;
  }
  fft64_reg<1>(zr, zi, ct, st);

  const float* pb = x + ((size_t)(b * 128 + h) * 128) * 768 + c;
  float* po = out + ((size_t)(b * 128 + h) * 128) * 768 + c;
  const float inv = 1.0f / 64.0f;
#pragma unroll
  for (int m = 0; m < 64; ++m) {
    po[(size_t)(2 * m) * 768]     = zr[m] * inv + pb[(size_t)(2 * m) * 768];
    po[(size_t)(2 * m + 1) * 768] = zi[m] * inv + pb[(size_t)(2 * m + 1) * 768];
  }
}

// ---------------------------------------------------------------------------
extern "C" void kernel_launch(void* const* d_in, const int* in_sizes, int n_in,
                              void* d_out, int out_size, void* d_ws, size_t ws_size,
                              hipStream_t stream) {
  const float* x  = (const float*)d_in[0];
  const float* w1 = (const float*)d_in[1];
  const float* b1 = (const float*)d_in[2];
  const float* w2 = (const float*)d_in[3];
  const float* b2 = (const float*)d_in[4];
  float* out = (float*)d_out;

  char* ws = (char*)d_ws;
  float2* F = (float2*)ws;                       // 4*128*65*768 float2 = 204,472,320 B
  size_t off = (size_t)204472320;
  unsigned short* W1 = (unsigned short*)(ws + off); off += 589824;
  unsigned short* W2 = (unsigned short*)(ws + off); off += 589824;
  float* B1 = (float*)(ws + off); off += 6144;
  float* B2 = (float*)(ws + off); off += 6144;

  k_prep<<<dim3(2316), dim3(256), 0, stream>>>(w1, b1, w2, b2, W1, W2, B1, B2);
  k_fwdw<<<dim3(1536), dim3(256), 0, stream>>>(x, F);
  k_ffth<-1><<<dim3(6240), dim3(256), 0, stream>>>(F);
  k_mlp<<<dim3(520, 8), dim3(256), 0, stream>>>((float*)F, W1, W2, B1, B2);
  k_ffth<1><<<dim3(6240), dim3(256), 0, stream>>>(F);
  k_invw<<<dim3(1536), dim3(256), 0, stream>>>(F, x, out);
}